// Round 10
// baseline (482.566 us; speedup 1.0000x reference)
//
#include <hip/hip_runtime.h>

#define N_NODES 100000
#define N_EDGES 1600000
#define NEG_SLOPE 0.2f
#define BN_EPS 1e-5f

typedef __attribute__((ext_vector_type(8))) short short8;
typedef __attribute__((ext_vector_type(4))) float floatx4;

// ---------------- workspace layout (bytes) ----------------
static const size_t OFF_AB   = 0;            // feats bf16 fragment-ordered [N_PAD,128]
static const size_t OFF_BB   = 25624576;     // weights bf16 fragment-ordered [512,128], B-PERMUTED
static const size_t OFF_H    = 25755648;     // h bf16 [N+1,256] (row N = sentinel zeros)
static const size_t OFF_RES  = 76956672;     // res+bias bf16 [N,256]
static const size_t OFF_EL   = 128156672;    // el [N+1,4] f32 (row N = -1e30 sentinel)
static const size_t OFF_ER   = 129757184;    // er [N,4] f32
static const size_t OFF_DEG  = 131357184;    // deg [N] i32
static const size_t OFF_RS   = 131757184;    // padded row_start [N+1] i32
static const size_t OFF_BN   = 132157568;    // bn accum [128] f32
static const size_t OFF_ESRC = 132557568;    // padded edge src ids [<=2.4M] i32
static const size_t OFF_BS   = 142157568;    // block sums [128] i32
// rank[e] scratch lives in d_out (first 6.4 MB; overwritten later by k_agg)

__device__ __forceinline__ unsigned short f2bf(float x) {
  unsigned int u = __float_as_uint(x);
  unsigned int r = (u + 0x7fffu + ((u >> 16) & 1u)) >> 16;   // RNE
  return (unsigned short)r;
}
__device__ __forceinline__ float bf2f(unsigned short u) {
  return __uint_as_float(((unsigned int)u) << 16);
}

// ---------------- fused pre-pass: cvt_a | count+rank | cvt_w | sentinels ----
// cvt_w uses a PERMUTED placement: weight row n goes to slab h*4+(n&3),
// pos (n>>2)&15 (h = half). Effect: MFMA fragment slot (nt,cn) computes
// true output dim cn*4+nt -> each thread's 4 fragment values are CONSECUTIVE
// dims -> k_mm stores become ushort4 (64 scalar 2B stores -> 16x 8B).
__global__ __launch_bounds__(256) void k_pre(
    const float* __restrict__ feats, const float* __restrict__ fc_w,
    const float* __restrict__ res_w, const int* __restrict__ dst,
    unsigned short* __restrict__ Ab, unsigned short* __restrict__ Bb,
    int* __restrict__ deg, unsigned short* __restrict__ hbuf,
    float* __restrict__ el, int* __restrict__ rank)
{
  const int b = blockIdx.x;
  if (b < 6256) {                                // ---- cvt_a: N_PAD*16 chunks
    int c = b * 256 + threadIdx.x;
    int r = c >> 4, j = c & 15;
    unsigned short v[8];
    if (r < N_NODES) {
      const float* p = feats + (size_t)r * 128 + j * 8;
      float4 a = *(const float4*)p, bb = *(const float4*)(p + 4);
      v[0]=f2bf(a.x); v[1]=f2bf(a.y); v[2]=f2bf(a.z); v[3]=f2bf(a.w);
      v[4]=f2bf(bb.x); v[5]=f2bf(bb.y); v[6]=f2bf(bb.z); v[7]=f2bf(bb.w);
    } else {
      for (int i = 0; i < 8; i++) v[i] = 0;
    }
    size_t idx = (size_t)(r >> 7) * 2048 + ((r >> 4) & 7) * 256 + (j >> 2) * 64
               + (r & 15) + 16 * (j & 3);
    *(short8*)(Ab + idx * 8) = *(short8*)v;
  } else if (b < 12506) {                        // ---- count degrees + rank
    int e = (b - 6256) * 256 + threadIdx.x;
    if (e < N_EDGES) rank[e] = atomicAdd(&deg[dst[e]], 1);
  } else if (b < 12538) {                        // ---- cvt_w: 8192 chunks
    int c = (b - 12506) * 256 + threadIdx.x;
    int n = c >> 4, j = c & 15;
    const float* W = (n < 256) ? (fc_w + (size_t)n * 128) : (res_w + (size_t)(n - 256) * 128);
    const float* p = W + j * 8;
    float4 a = *(const float4*)p, bb = *(const float4*)(p + 4);
    unsigned short v[8];
    v[0]=f2bf(a.x); v[1]=f2bf(a.y); v[2]=f2bf(a.z); v[3]=f2bf(a.w);
    v[4]=f2bf(bb.x); v[5]=f2bf(bb.y); v[6]=f2bf(bb.z); v[7]=f2bf(bb.w);
    // permuted placement: slab = h*4 + (n&3), pos = (n>>2)&15
    size_t idx = (size_t)(n >> 7) * 2048
               + (size_t)(((n >> 6) & 1) * 4 + (n & 3)) * 256
               + (j >> 2) * 64 + ((n >> 2) & 15) + 16 * (j & 3);
    *(short8*)(Bb + idx * 8) = *(short8*)v;
  } else {                                       // ---- sentinel row init
    const int t = threadIdx.x;
    hbuf[(size_t)N_NODES * 256 + t] = 0;         // zero h row for dummy src
    if (t < 4) el[N_NODES * 4 + t] = -1e30f;     // weight-0 logit for dummy src
  }
}

// ---------------- CSR build (rows PADDED to multiples of 4) ----------------
__global__ __launch_bounds__(256) void k_scan1(const int* __restrict__ deg,
                                               int* __restrict__ rs, int* __restrict__ bsums)
{
  __shared__ int tmp[256];
  const int t = threadIdx.x;
  const int base = blockIdx.x * 1024 + t * 4;
  int v0 = 0, v1 = 0, v2 = 0, v3 = 0;
  if (base + 0 < N_NODES) v0 = (deg[base + 0] + 3) & ~3;
  if (base + 1 < N_NODES) v1 = (deg[base + 1] + 3) & ~3;
  if (base + 2 < N_NODES) v2 = (deg[base + 2] + 3) & ~3;
  if (base + 3 < N_NODES) v3 = (deg[base + 3] + 3) & ~3;
  const int tsum = v0 + v1 + v2 + v3;
  tmp[t] = tsum;
  __syncthreads();
  for (int o = 1; o < 256; o <<= 1) {
    int x = (t >= o) ? tmp[t - o] : 0;
    __syncthreads();
    tmp[t] += x;
    __syncthreads();
  }
  const int excl = tmp[t] - tsum;
  if (base + 0 < N_NODES) rs[base + 0] = excl;
  if (base + 1 < N_NODES) rs[base + 1] = excl + v0;
  if (base + 2 < N_NODES) rs[base + 2] = excl + v0 + v1;
  if (base + 3 < N_NODES) rs[base + 3] = excl + v0 + v1 + v2;
  if (t == 255) bsums[blockIdx.x] = tmp[t];
}

// finalize padded offsets + pad/tail sentinel esrc
__global__ __launch_bounds__(256) void k_scan3(int* __restrict__ rs,
                                               const int* __restrict__ bsums,
                                               const int* __restrict__ deg,
                                               int* __restrict__ esrc)
{
  __shared__ int sb[128];
  const int t = threadIdx.x;
  int raw = 0;
  if (t < 128) { raw = (t < 98) ? bsums[t] : 0; sb[t] = raw; }
  __syncthreads();
  for (int o = 1; o < 128; o <<= 1) {
    int x = (t >= o && t < 128) ? sb[t - o] : 0;
    __syncthreads();
    if (t < 128) sb[t] += x;
    __syncthreads();
  }
  if (t < 128) sb[t] -= raw;   // exclusive
  __syncthreads();
  const int i = blockIdx.x * 256 + t;
  if (i < N_NODES) {
    int v = rs[i] + sb[i >> 10];
    rs[i] = v;
    const int d = deg[i];
    const int pd = (d + 3) & ~3;
    for (int j = d; j < pd; j++) esrc[v + j] = N_NODES;   // weight-0 dummies
    if (i == N_NODES - 1) {
      rs[N_NODES] = v + pd;
      for (int j = 0; j < 16; j++) esrc[v + pd + j] = N_NODES;  // guard tail
    }
  }
}

// ---------------- atomic-free edge placement ----------------
__global__ __launch_bounds__(256) void k_place(const int* __restrict__ src,
                                               const int* __restrict__ dst,
                                               const int* __restrict__ rs,
                                               const int* __restrict__ rank,
                                               int* __restrict__ esrc)
{
  int e = blockIdx.x * 256 + threadIdx.x;
  if (e >= N_EDGES) return;
  esrc[rs[dst[e]] + rank[e]] = src[e];
}

// ---------------- MFMA projection + fused el/er -----------------------------
// grid (782, 2): block stages A once, inner loop computes h-half and res-half.
// B-permuted Bb packing -> thread's 4 fragment cols are consecutive dims:
// epilogue stores are ushort4 (16 per thread per half), bias/attn loads float4.
__global__ __launch_bounds__(256) void k_mm(
    const unsigned short* __restrict__ Ab, const unsigned short* __restrict__ Bb,
    const float* __restrict__ bias, const float* __restrict__ attn_l,
    const float* __restrict__ attn_r,
    unsigned short* __restrict__ hbuf, unsigned short* __restrict__ resbuf,
    float* __restrict__ el, float* __restrict__ er)
{
  __shared__ unsigned short sA[16384];  // 32 KB, fragment-ordered A block
  const int tid = threadIdx.x;
  const int w = tid >> 6, L = tid & 63;
  const int blk = blockIdx.x;

  {  // stage A: contiguous 32 KB, global_load_lds width 16
    const unsigned short* ga = Ab + (size_t)blk * 16384;
    #pragma unroll
    for (int i = 0; i < 8; i++) {
      int off = (i * 256 + w * 64) * 8;
      __builtin_amdgcn_global_load_lds(
          (const __attribute__((address_space(1))) unsigned int*)(ga + off + L * 8),
          (__attribute__((address_space(3))) unsigned int*)(sA + off),
          16, 0, 0);
    }
  }
  const int mh = w & 1, nh = w >> 1;
  __syncthreads();

  for (int wb = 0; wb < 2; ++wb) {
    const int nb = blockIdx.y + wb * 2;
    floatx4 acc[4][4] = {};
    const unsigned short* gb = Bb + ((size_t)nb * 2048 + nh * 4 * 256) * 8 + L * 8;
    #pragma unroll
    for (int s = 0; s < 4; s++) {
      short8 a[4], b[4];
      #pragma unroll
      for (int t = 0; t < 4; t++)
        a[t] = *(const short8*)(sA + ((mh * 4 + t) * 256 + s * 64 + L) * 8);
      #pragma unroll
      for (int t = 0; t < 4; t++)
        b[t] = *(const short8*)(gb + ((size_t)t * 256 + s * 64) * 8);
      #pragma unroll
      for (int mt = 0; mt < 4; mt++)
        #pragma unroll
        for (int nt = 0; nt < 4; nt++)
          acc[mt][nt] = __builtin_amdgcn_mfma_f32_16x16x32_bf16(a[mt], b[nt], acc[mt][nt], 0, 0, 0);
    }

    const int q = L >> 4, cn = L & 15;
    const int r0 = blk * 128 + mh * 64;
    if (nb < 2) {
      const int head = nb * 2 + nh;            // this wave owns one full head
      const int col0 = nb * 128 + nh * 64;
      // permuted mapping: fragment slot (nt,cn) = true dim cn*4+nt
      const float4 al4 = *(const float4*)(attn_l + head * 64 + cn * 4);
      const float4 ar4 = *(const float4*)(attn_r + head * 64 + cn * 4);
      #pragma unroll
      for (int mt = 0; mt < 4; mt++)
        #pragma unroll
        for (int r = 0; r < 4; r++) {
          const int row = r0 + mt * 16 + q * 4 + r;
          float pl = acc[mt][0][r] * al4.x + acc[mt][1][r] * al4.y
                   + acc[mt][2][r] * al4.z + acc[mt][3][r] * al4.w;
          float pr = acc[mt][0][r] * ar4.x + acc[mt][1][r] * ar4.y
                   + acc[mt][2][r] * ar4.z + acc[mt][3][r] * ar4.w;
          #pragma unroll
          for (int o = 1; o < 16; o <<= 1) {
            pl += __shfl_xor(pl, o, 64);
            pr += __shfl_xor(pr, o, 64);
          }
          if (row < N_NODES) {
            ushort4 hv4;
            hv4.x = f2bf(acc[mt][0][r]); hv4.y = f2bf(acc[mt][1][r]);
            hv4.z = f2bf(acc[mt][2][r]); hv4.w = f2bf(acc[mt][3][r]);
            *(ushort4*)(hbuf + (size_t)row * 256 + col0 + cn * 4) = hv4;
            if (cn == 0) {
              el[row * 4 + head] = pl;
              er[row * 4 + head] = pr;
            }
          }
        }
    } else {
      const int rc0 = (nb - 2) * 128 + nh * 64;
      const float4 b4 = *(const float4*)(bias + rc0 + cn * 4);
      #pragma unroll
      for (int mt = 0; mt < 4; mt++)
        #pragma unroll
        for (int r = 0; r < 4; r++) {
          const int row = r0 + mt * 16 + q * 4 + r;
          if (row < N_NODES) {
            ushort4 rv4;
            rv4.x = f2bf(acc[mt][0][r] + b4.x);
            rv4.y = f2bf(acc[mt][1][r] + b4.y);
            rv4.z = f2bf(acc[mt][2][r] + b4.z);
            rv4.w = f2bf(acc[mt][3][r] + b4.w);
            *(ushort4*)(resbuf + (size_t)row * 256 + rc0 + cn * 4) = rv4;
          }
        }
    }
  }
}

// ---------------- fused softmax + aggregation + residual/ELU/head-mean ------
// PROVEN round-2 structure (143 us @ r9): flat padded-CSR stream per wave,
// 4-wide batches, depth-4 named-register rotation, GUARDED loads, no fences,
// __launch_bounds__(256, 4). UNCHANGED this round (control).
#define RFL(x) __builtin_amdgcn_readfirstlane(x)

#define LOADSN4(SN, PP) do { SN = *(const int4*)(esrc + (PP)); } while (0)

#define GATHER4(EV, HV, SN) do { \
  const int g0_ = RFL(SN.x), g1_ = RFL(SN.y), g2_ = RFL(SN.z), g3_ = RFL(SN.w); \
  HV##0 = *(const ushort4*)(hbuf + (size_t)g0_ * 256 + lane4); \
  HV##1 = *(const ushort4*)(hbuf + (size_t)g1_ * 256 + lane4); \
  HV##2 = *(const ushort4*)(hbuf + (size_t)g2_ * 256 + lane4); \
  HV##3 = *(const ushort4*)(hbuf + (size_t)g3_ * 256 + lane4); \
  EV##0 = el[g0_ * 4 + head]; \
  EV##1 = el[g1_ * 4 + head]; \
  EV##2 = el[g2_ * 4 + head]; \
  EV##3 = el[g3_ * 4 + head]; \
} while (0)

#define EDGE1(EVi, HVi) do { \
  float e_ = EVi + ern; \
  e_ = (e_ > 0.f) ? e_ : NEG_SLOPE * e_; \
  const float w_ = __expf(e_); \
  ssum += w_; \
  acc.x = fmaf(w_, bf2f(HVi.x), acc.x); \
  acc.y = fmaf(w_, bf2f(HVi.y), acc.y); \
  acc.z = fmaf(w_, bf2f(HVi.z), acc.z); \
  acc.w = fmaf(w_, bf2f(HVi.w), acc.w); \
} while (0)

#define COMPUTE4(EV, HV) do { \
  EDGE1(EV##0, HV##0); EDGE1(EV##1, HV##1); \
  EDGE1(EV##2, HV##2); EDGE1(EV##3, HV##3); \
} while (0)

#define FIN(ND) do { \
  const float inv_ = (ssum > 0.f) ? (1.0f / ssum) : 0.f; \
  float vx_ = fmaf(acc.x, inv_, bf2f(rv_cur.x)); \
  float vy_ = fmaf(acc.y, inv_, bf2f(rv_cur.y)); \
  float vz_ = fmaf(acc.z, inv_, bf2f(rv_cur.z)); \
  float vw_ = fmaf(acc.w, inv_, bf2f(rv_cur.w)); \
  vx_ = (vx_ > 0.f) ? vx_ : (__expf(vx_) - 1.f); \
  vy_ = (vy_ > 0.f) ? vy_ : (__expf(vy_) - 1.f); \
  vz_ = (vz_ > 0.f) ? vz_ : (__expf(vz_) - 1.f); \
  vw_ = (vw_ > 0.f) ? vw_ : (__expf(vw_) - 1.f); \
  vx_ += __shfl_xor(vx_, 16, 64); vx_ += __shfl_xor(vx_, 32, 64); \
  vy_ += __shfl_xor(vy_, 16, 64); vy_ += __shfl_xor(vy_, 32, 64); \
  vz_ += __shfl_xor(vz_, 16, 64); vz_ += __shfl_xor(vz_, 32, 64); \
  vw_ += __shfl_xor(vw_, 16, 64); vw_ += __shfl_xor(vw_, 32, 64); \
  if (lane < 16) { \
    float4 o_; \
    o_.x = vx_ * 0.25f; o_.y = vy_ * 0.25f; o_.z = vz_ * 0.25f; o_.w = vw_ * 0.25f; \
    *(float4*)(out + (size_t)(ND) * 64 + lane4) = o_; \
  } \
} while (0)

#define BOUNDARY() \
  while (p == nend) { \
    FIN(nu); \
    acc.x = 0.f; acc.y = 0.f; acc.z = 0.f; acc.w = 0.f; ssum = 0.f; \
    nu++; \
    nend = nendN; ern = ernN; rv_cur = rvN; \
    const int f1_ = (nu + 1 < N_NODES) ? (nu + 1) : (N_NODES - 1); \
    const int f2_ = (nu + 2 <= N_NODES) ? (nu + 2) : N_NODES; \
    nendN = RFL(rs[f2_]); \
    ernN = er[f1_ * 4 + head]; \
    rvN = *(const ushort4*)(resbuf + (size_t)f1_ * 256 + lane4); \
  }

__global__ __launch_bounds__(256, 4) void k_agg(
    const unsigned short* __restrict__ hbuf, const unsigned short* __restrict__ resbuf,
    const float* __restrict__ el, const float* __restrict__ er,
    const int* __restrict__ rs, const int* __restrict__ esrc,
    float* __restrict__ out)
{
  const int lane = threadIdx.x & 63;
  const int head = lane >> 4;
  const int lane4 = lane * 4;
  const int wid = blockIdx.x * 4 + (threadIdx.x >> 6);
  const int nW = gridDim.x * 4;

  const int n0 = (int)(((long long)wid * N_NODES) / nW);
  const int n1 = (int)(((long long)(wid + 1) * N_NODES) / nW);
  if (n0 >= n1) return;

  int nu = RFL(n0);
  const int p_end = RFL(rs[n1]);
  int nend = RFL(rs[nu + 1]);
  int f1 = (nu + 1 < N_NODES) ? (nu + 1) : (N_NODES - 1);
  int f2 = (nu + 2 <= N_NODES) ? (nu + 2) : N_NODES;
  int nendN = RFL(rs[f2]);
  float ern  = er[nu * 4 + head];
  float ernN = er[f1 * 4 + head];
  ushort4 rv_cur = *(const ushort4*)(resbuf + (size_t)nu * 256 + lane4);
  ushort4 rvN    = *(const ushort4*)(resbuf + (size_t)f1 * 256 + lane4);

  float4 acc = make_float4(0.f, 0.f, 0.f, 0.f);
  float ssum = 0.f;

  int4 snA, snB, snC, snD;
  float evA0, evA1, evA2, evA3, evB0, evB1, evB2, evB3;
  float evC0, evC1, evC2, evC3, evD0, evD1, evD2, evD3;
  ushort4 hvA0, hvA1, hvA2, hvA3, hvB0, hvB1, hvB2, hvB3;
  ushort4 hvC0, hvC1, hvC2, hvC3, hvD0, hvD1, hvD2, hvD3;

  int p = RFL(rs[nu]);
  if (p      < p_end) { LOADSN4(snA, p);      GATHER4(evA, hvA, snA); }
  if (p + 4  < p_end) { LOADSN4(snB, p + 4);  GATHER4(evB, hvB, snB); }
  if (p + 8  < p_end) { LOADSN4(snC, p + 8);  GATHER4(evC, hvC, snC); }
  if (p + 12 < p_end) { LOADSN4(snD, p + 12); }

  while (p < p_end) {
    // ---- step A (batch p)
    if (p + 12 < p_end) GATHER4(evD, hvD, snD);
    if (p + 16 < p_end) LOADSN4(snA, p + 16);
    BOUNDARY();
    COMPUTE4(evA, hvA);
    p += 4; if (p >= p_end) break;
    // ---- step B
    if (p + 12 < p_end) GATHER4(evA, hvA, snA);
    if (p + 16 < p_end) LOADSN4(snB, p + 16);
    BOUNDARY();
    COMPUTE4(evB, hvB);
    p += 4; if (p >= p_end) break;
    // ---- step C
    if (p + 12 < p_end) GATHER4(evB, hvB, snB);
    if (p + 16 < p_end) LOADSN4(snC, p + 16);
    BOUNDARY();
    COMPUTE4(evC, hvC);
    p += 4; if (p >= p_end) break;
    // ---- step D
    if (p + 12 < p_end) GATHER4(evC, hvC, snC);
    if (p + 16 < p_end) LOADSN4(snD, p + 16);
    BOUNDARY();
    COMPUTE4(evD, hvD);
    p += 4;
  }

  // drain: finalize last node + trailing zero-degree nodes
  while (nu < n1) {
    FIN(nu);
    acc.x = 0.f; acc.y = 0.f; acc.z = 0.f; acc.w = 0.f; ssum = 0.f;
    nu++;
    if (nu < n1) rv_cur = *(const ushort4*)(resbuf + (size_t)nu * 256 + lane4);
  }
}

// ---------------- BN stats over out (separate small pass) ----------------
__global__ __launch_bounds__(256) void k_bn_stats(const float* __restrict__ out,
                                                  float* __restrict__ bn)
{
  const int t = threadIdx.x;
  const int c4 = (t & 15) * 4;
  const int rg = t >> 4;
  float4 s = make_float4(0.f, 0.f, 0.f, 0.f);
  float4 q = make_float4(0.f, 0.f, 0.f, 0.f);
  for (int row = blockIdx.x * 16 + rg; row < N_NODES; row += gridDim.x * 16) {
    float4 v = *(const float4*)(out + (size_t)row * 64 + c4);
    s.x += v.x; s.y += v.y; s.z += v.z; s.w += v.w;
    q.x += v.x * v.x; q.y += v.y * v.y; q.z += v.z * v.z; q.w += v.w * v.w;
  }
  __shared__ float ls[64], lq[64];
  if (t < 64) { ls[t] = 0.f; lq[t] = 0.f; }
  __syncthreads();
  atomicAdd(&ls[c4 + 0], s.x); atomicAdd(&ls[c4 + 1], s.y);
  atomicAdd(&ls[c4 + 2], s.z); atomicAdd(&ls[c4 + 3], s.w);
  atomicAdd(&lq[c4 + 0], q.x); atomicAdd(&lq[c4 + 1], q.y);
  atomicAdd(&lq[c4 + 2], q.z); atomicAdd(&lq[c4 + 3], q.w);
  __syncthreads();
  if (t < 64) {
    atomicAdd(&bn[t], ls[t]);
    atomicAdd(&bn[64 + t], lq[t]);
  }
}

// ---------------- batchnorm apply ----------------
__global__ __launch_bounds__(256) void k_bn_apply(float* __restrict__ out,
                                                  const float* __restrict__ bn,
                                                  const float* __restrict__ gamma,
                                                  const float* __restrict__ beta)
{
  __shared__ float sc[64], sh[64];
  const int t = threadIdx.x;
  if (t < 64) {
    float mean = bn[t] * (1.0f / N_NODES);
    float var = bn[64 + t] * (1.0f / N_NODES) - mean * mean;
    float s = gamma[t] * rsqrtf(var + BN_EPS);
    sc[t] = s;
    sh[t] = beta[t] - mean * s;
  }
  __syncthreads();
  const int i = blockIdx.x * 256 + t;
  if (i >= N_NODES * 16) return;
  const int d0 = (i & 15) * 4;
  float4 v = *(float4*)(out + (size_t)i * 4);
  v.x = fmaf(v.x, sc[d0 + 0], sh[d0 + 0]);
  v.y = fmaf(v.y, sc[d0 + 1], sh[d0 + 1]);
  v.z = fmaf(v.z, sc[d0 + 2], sh[d0 + 2]);
  v.w = fmaf(v.w, sc[d0 + 3], sh[d0 + 3]);
  *(float4*)(out + (size_t)i * 4) = v;
}

extern "C" void kernel_launch(void* const* d_in, const int* in_sizes, int n_in,
                              void* d_out, int out_size, void* d_ws, size_t ws_size,
                              hipStream_t stream)
{
  const float* feats  = (const float*)d_in[0];
  const int*   src    = (const int*)d_in[1];
  const int*   dst    = (const int*)d_in[2];
  const float* fc_w   = (const float*)d_in[3];
  const float* attn_l = (const float*)d_in[4];
  const float* attn_r = (const float*)d_in[5];
  const float* res_w  = (const float*)d_in[6];
  const float* bias   = (const float*)d_in[7];
  const float* gamma  = (const float*)d_in[8];
  const float* beta   = (const float*)d_in[9];

  char* ws = (char*)d_ws;
  unsigned short* Ab     = (unsigned short*)(ws + OFF_AB);
  unsigned short* Bb     = (unsigned short*)(ws + OFF_BB);
  unsigned short* hbuf   = (unsigned short*)(ws + OFF_H);
  unsigned short* resbuf = (unsigned short*)(ws + OFF_RES);
  float* elb    = (float*)(ws + OFF_EL);
  float* erb    = (float*)(ws + OFF_ER);
  int*   deg    = (int*)(ws + OFF_DEG);
  int*   rsb    = (int*)(ws + OFF_RS);
  float* bnb    = (float*)(ws + OFF_BN);
  int*   esrc   = (int*)(ws + OFF_ESRC);
  int*   bsums  = (int*)(ws + OFF_BS);
  float* outp   = (float*)d_out;
  int*   rankp  = (int*)d_out;          // scratch: first 6.4 MB of out

  hipMemsetAsync(deg, 0, N_NODES * sizeof(int), stream);
  hipMemsetAsync(bnb, 0, 128 * sizeof(float), stream);

  k_pre<<<12539, 256, 0, stream>>>(feats, fc_w, res_w, dst, Ab, Bb, deg, hbuf, elb, rankp);
  k_scan1<<<98, 256, 0, stream>>>(deg, rsb, bsums);
  k_scan3<<<391, 256, 0, stream>>>(rsb, bsums, deg, esrc);
  k_place<<<6250, 256, 0, stream>>>(src, dst, rsb, rankp, esrc);
  k_mm<<<dim3(782, 2), 256, 0, stream>>>(Ab, Bb, bias, attn_l, attn_r,
                                         hbuf, resbuf, elb, erb);
  k_agg<<<2048, 256, 0, stream>>>(hbuf, resbuf, elb, erb, rsb, esrc, outp);
  k_bn_stats<<<256, 256, 0, stream>>>(outp, bnb);
  k_bn_apply<<<6250, 256, 0, stream>>>(outp, bnb, gamma, beta);
}

// Round 11
// 458.673 us; speedup vs baseline: 1.0521x; 1.0521x over previous
//
#include <hip/hip_runtime.h>

#define N_NODES 100000
#define N_EDGES 1600000
#define NEG_SLOPE 0.2f
#define BN_EPS 1e-5f

typedef __attribute__((ext_vector_type(8))) short short8;
typedef __attribute__((ext_vector_type(4))) float floatx4;

// ---------------- workspace layout (bytes) ----------------
static const size_t OFF_AB   = 0;            // feats bf16 fragment-ordered [N_PAD,128]
static const size_t OFF_BB   = 25624576;     // weights bf16 fragment-ordered [512,128]
static const size_t OFF_H    = 25755648;     // h bf16 [N+1,256] (row N = sentinel zeros)
static const size_t OFF_RES  = 76956672;     // res+bias bf16 [N,256]
static const size_t OFF_EL   = 128156672;    // el [N+1,4] f32 (row N = -1e30 sentinel)
static const size_t OFF_ER   = 129757184;    // er [N,4] f32
static const size_t OFF_DEG  = 131357184;    // deg [N] i32
static const size_t OFF_RS   = 131757184;    // padded row_start [N+1] i32
static const size_t OFF_BN   = 132157568;    // bn accum [128] f32
static const size_t OFF_ESRC = 132557568;    // padded edge src ids [<=2.4M] i32
static const size_t OFF_BS   = 142157568;    // block sums [128] i32
// rank[e] scratch lives in d_out (first 6.4 MB; overwritten later by k_agg)

__device__ __forceinline__ unsigned short f2bf(float x) {
  unsigned int u = __float_as_uint(x);
  unsigned int r = (u + 0x7fffu + ((u >> 16) & 1u)) >> 16;   // RNE
  return (unsigned short)r;
}
__device__ __forceinline__ float bf2f(unsigned short u) {
  return __uint_as_float(((unsigned int)u) << 16);
}

// ---------------- fused pre-pass: cvt_a | count+rank | cvt_w | sentinels ----
// count role: atomicAdd's RETURN is the within-row rank -> placement pass
// needs no atomics.
__global__ __launch_bounds__(256) void k_pre(
    const float* __restrict__ feats, const float* __restrict__ fc_w,
    const float* __restrict__ res_w, const int* __restrict__ dst,
    unsigned short* __restrict__ Ab, unsigned short* __restrict__ Bb,
    int* __restrict__ deg, unsigned short* __restrict__ hbuf,
    float* __restrict__ el, int* __restrict__ rank)
{
  const int b = blockIdx.x;
  if (b < 6256) {                                // ---- cvt_a: N_PAD*16 chunks
    int c = b * 256 + threadIdx.x;
    int r = c >> 4, j = c & 15;
    unsigned short v[8];
    if (r < N_NODES) {
      const float* p = feats + (size_t)r * 128 + j * 8;
      float4 a = *(const float4*)p, bb = *(const float4*)(p + 4);
      v[0]=f2bf(a.x); v[1]=f2bf(a.y); v[2]=f2bf(a.z); v[3]=f2bf(a.w);
      v[4]=f2bf(bb.x); v[5]=f2bf(bb.y); v[6]=f2bf(bb.z); v[7]=f2bf(bb.w);
    } else {
      for (int i = 0; i < 8; i++) v[i] = 0;
    }
    size_t idx = (size_t)(r >> 7) * 2048 + ((r >> 4) & 7) * 256 + (j >> 2) * 64
               + (r & 15) + 16 * (j & 3);
    *(short8*)(Ab + idx * 8) = *(short8*)v;
  } else if (b < 12506) {                        // ---- count degrees + rank
    int e = (b - 6256) * 256 + threadIdx.x;
    if (e < N_EDGES) rank[e] = atomicAdd(&deg[dst[e]], 1);
  } else if (b < 12538) {                        // ---- cvt_w: 8192 chunks
    int c = (b - 12506) * 256 + threadIdx.x;
    int n = c >> 4, j = c & 15;
    const float* W = (n < 256) ? (fc_w + (size_t)n * 128) : (res_w + (size_t)(n - 256) * 128);
    const float* p = W + j * 8;
    float4 a = *(const float4*)p, bb = *(const float4*)(p + 4);
    unsigned short v[8];
    v[0]=f2bf(a.x); v[1]=f2bf(a.y); v[2]=f2bf(a.z); v[3]=f2bf(a.w);
    v[4]=f2bf(bb.x); v[5]=f2bf(bb.y); v[6]=f2bf(bb.z); v[7]=f2bf(bb.w);
    size_t idx = (size_t)(n >> 7) * 2048 + ((n >> 4) & 7) * 256 + (j >> 2) * 64
               + (n & 15) + 16 * (j & 3);
    *(short8*)(Bb + idx * 8) = *(short8*)v;
  } else {                                       // ---- sentinel row init
    const int t = threadIdx.x;
    hbuf[(size_t)N_NODES * 256 + t] = 0;         // zero h row for dummy src
    if (t < 4) el[N_NODES * 4 + t] = -1e30f;     // weight-0 logit for dummy src
  }
}

// ---------------- CSR build (rows PADDED to multiples of 4) ----------------
__global__ __launch_bounds__(256) void k_scan1(const int* __restrict__ deg,
                                               int* __restrict__ rs, int* __restrict__ bsums)
{
  __shared__ int tmp[256];
  const int t = threadIdx.x;
  const int base = blockIdx.x * 1024 + t * 4;
  int v0 = 0, v1 = 0, v2 = 0, v3 = 0;
  if (base + 0 < N_NODES) v0 = (deg[base + 0] + 3) & ~3;
  if (base + 1 < N_NODES) v1 = (deg[base + 1] + 3) & ~3;
  if (base + 2 < N_NODES) v2 = (deg[base + 2] + 3) & ~3;
  if (base + 3 < N_NODES) v3 = (deg[base + 3] + 3) & ~3;
  const int tsum = v0 + v1 + v2 + v3;
  tmp[t] = tsum;
  __syncthreads();
  for (int o = 1; o < 256; o <<= 1) {
    int x = (t >= o) ? tmp[t - o] : 0;
    __syncthreads();
    tmp[t] += x;
    __syncthreads();
  }
  const int excl = tmp[t] - tsum;
  if (base + 0 < N_NODES) rs[base + 0] = excl;
  if (base + 1 < N_NODES) rs[base + 1] = excl + v0;
  if (base + 2 < N_NODES) rs[base + 2] = excl + v0 + v1;
  if (base + 3 < N_NODES) rs[base + 3] = excl + v0 + v1 + v2;
  if (t == 255) bsums[blockIdx.x] = tmp[t];
}

// finalize padded offsets + pad/tail sentinel esrc
__global__ __launch_bounds__(256) void k_scan3(int* __restrict__ rs,
                                               const int* __restrict__ bsums,
                                               const int* __restrict__ deg,
                                               int* __restrict__ esrc)
{
  __shared__ int sb[128];
  const int t = threadIdx.x;
  int raw = 0;
  if (t < 128) { raw = (t < 98) ? bsums[t] : 0; sb[t] = raw; }
  __syncthreads();
  for (int o = 1; o < 128; o <<= 1) {
    int x = (t >= o && t < 128) ? sb[t - o] : 0;
    __syncthreads();
    if (t < 128) sb[t] += x;
    __syncthreads();
  }
  if (t < 128) sb[t] -= raw;   // exclusive
  __syncthreads();
  const int i = blockIdx.x * 256 + t;
  if (i < N_NODES) {
    int v = rs[i] + sb[i >> 10];
    rs[i] = v;
    const int d = deg[i];
    const int pd = (d + 3) & ~3;
    for (int j = d; j < pd; j++) esrc[v + j] = N_NODES;   // weight-0 dummies
    if (i == N_NODES - 1) {
      rs[N_NODES] = v + pd;
      for (int j = 0; j < 16; j++) esrc[v + pd + j] = N_NODES;  // guard tail
    }
  }
}

// ---------------- atomic-free edge placement ----------------
__global__ __launch_bounds__(256) void k_place(const int* __restrict__ src,
                                               const int* __restrict__ dst,
                                               const int* __restrict__ rs,
                                               const int* __restrict__ rank,
                                               int* __restrict__ esrc)
{
  int e = blockIdx.x * 256 + threadIdx.x;
  if (e >= N_EDGES) return;
  esrc[rs[dst[e]] + rank[e]] = src[e];
}

// ---------------- MFMA projection + fused el/er -----------------------------
// grid 782 (1D): block stages A ONCE, inner loop over all 4 output panels
// (nb = 0..3) -> Ab HBM fetch halves vs the (782,2) version.
__global__ __launch_bounds__(256) void k_mm(
    const unsigned short* __restrict__ Ab, const unsigned short* __restrict__ Bb,
    const float* __restrict__ bias, const float* __restrict__ attn_l,
    const float* __restrict__ attn_r,
    unsigned short* __restrict__ hbuf, unsigned short* __restrict__ resbuf,
    float* __restrict__ el, float* __restrict__ er)
{
  __shared__ unsigned short sA[16384];  // 32 KB, fragment-ordered A block
  const int tid = threadIdx.x;
  const int w = tid >> 6, L = tid & 63;
  const int blk = blockIdx.x;

  {  // stage A: contiguous 32 KB, global_load_lds width 16
    const unsigned short* ga = Ab + (size_t)blk * 16384;
    #pragma unroll
    for (int i = 0; i < 8; i++) {
      int off = (i * 256 + w * 64) * 8;
      __builtin_amdgcn_global_load_lds(
          (const __attribute__((address_space(1))) unsigned int*)(ga + off + L * 8),
          (__attribute__((address_space(3))) unsigned int*)(sA + off),
          16, 0, 0);
    }
  }
  const int mh = w & 1, nh = w >> 1;
  __syncthreads();

  for (int nb = 0; nb < 4; ++nb) {
    floatx4 acc[4][4] = {};
    const unsigned short* gb = Bb + ((size_t)nb * 2048 + nh * 4 * 256) * 8 + L * 8;
    #pragma unroll
    for (int s = 0; s < 4; s++) {
      short8 a[4], b[4];
      #pragma unroll
      for (int t = 0; t < 4; t++)
        a[t] = *(const short8*)(sA + ((mh * 4 + t) * 256 + s * 64 + L) * 8);
      #pragma unroll
      for (int t = 0; t < 4; t++)
        b[t] = *(const short8*)(gb + ((size_t)t * 256 + s * 64) * 8);
      #pragma unroll
      for (int mt = 0; mt < 4; mt++)
        #pragma unroll
        for (int nt = 0; nt < 4; nt++)
          acc[mt][nt] = __builtin_amdgcn_mfma_f32_16x16x32_bf16(a[mt], b[nt], acc[mt][nt], 0, 0, 0);
    }

    const int q = L >> 4, cn = L & 15;
    const int r0 = blk * 128 + mh * 64;
    if (nb < 2) {
      const int head = nb * 2 + nh;            // this wave owns one full head
      const int col0 = nb * 128 + nh * 64;
      float al[4], ar[4];
      #pragma unroll
      for (int nt = 0; nt < 4; nt++) {
        al[nt] = attn_l[head * 64 + nt * 16 + cn];
        ar[nt] = attn_r[head * 64 + nt * 16 + cn];
      }
      #pragma unroll
      for (int mt = 0; mt < 4; mt++)
        #pragma unroll
        for (int r = 0; r < 4; r++) {
          const int row = r0 + mt * 16 + q * 4 + r;
          float pl = 0.f, pr = 0.f;
          #pragma unroll
          for (int nt = 0; nt < 4; nt++) {
            pl = fmaf(acc[mt][nt][r], al[nt], pl);
            pr = fmaf(acc[mt][nt][r], ar[nt], pr);
          }
          #pragma unroll
          for (int o = 1; o < 16; o <<= 1) {
            pl += __shfl_xor(pl, o, 64);
            pr += __shfl_xor(pr, o, 64);
          }
          if (row < N_NODES) {
            #pragma unroll
            for (int nt = 0; nt < 4; nt++)
              hbuf[(size_t)row * 256 + col0 + nt * 16 + cn] = f2bf(acc[mt][nt][r]);
            if (cn == 0) {
              el[row * 4 + head] = pl;
              er[row * 4 + head] = pr;
            }
          }
        }
    } else {
      const int rc0 = (nb - 2) * 128 + nh * 64;
      #pragma unroll
      for (int mt = 0; mt < 4; mt++)
        #pragma unroll
        for (int r = 0; r < 4; r++) {
          const int row = r0 + mt * 16 + q * 4 + r;
          if (row < N_NODES)
            #pragma unroll
            for (int nt = 0; nt < 4; nt++) {
              float v = acc[mt][nt][r] + bias[rc0 + nt * 16 + cn];
              resbuf[(size_t)row * 256 + rc0 + nt * 16 + cn] = f2bf(v);
            }
        }
    }
  }
}

// ---------------- fused softmax + aggregation + residual/ELU/head-mean ------
// PROVEN round-2/9 structure (143.8 us): flat padded-CSR stream per wave,
// 4-wide batches, depth-4 named-register rotation, GUARDED loads, no fences,
// __launch_bounds__(256, 4). Grid 4096 (was 2048) for tail backfill.
#define RFL(x) __builtin_amdgcn_readfirstlane(x)

#define LOADSN4(SN, PP) do { SN = *(const int4*)(esrc + (PP)); } while (0)

#define GATHER4(EV, HV, SN) do { \
  const int g0_ = RFL(SN.x), g1_ = RFL(SN.y), g2_ = RFL(SN.z), g3_ = RFL(SN.w); \
  HV##0 = *(const ushort4*)(hbuf + (size_t)g0_ * 256 + lane4); \
  HV##1 = *(const ushort4*)(hbuf + (size_t)g1_ * 256 + lane4); \
  HV##2 = *(const ushort4*)(hbuf + (size_t)g2_ * 256 + lane4); \
  HV##3 = *(const ushort4*)(hbuf + (size_t)g3_ * 256 + lane4); \
  EV##0 = el[g0_ * 4 + head]; \
  EV##1 = el[g1_ * 4 + head]; \
  EV##2 = el[g2_ * 4 + head]; \
  EV##3 = el[g3_ * 4 + head]; \
} while (0)

#define EDGE1(EVi, HVi) do { \
  float e_ = EVi + ern; \
  e_ = (e_ > 0.f) ? e_ : NEG_SLOPE * e_; \
  const float w_ = __expf(e_); \
  ssum += w_; \
  acc.x = fmaf(w_, bf2f(HVi.x), acc.x); \
  acc.y = fmaf(w_, bf2f(HVi.y), acc.y); \
  acc.z = fmaf(w_, bf2f(HVi.z), acc.z); \
  acc.w = fmaf(w_, bf2f(HVi.w), acc.w); \
} while (0)

#define COMPUTE4(EV, HV) do { \
  EDGE1(EV##0, HV##0); EDGE1(EV##1, HV##1); \
  EDGE1(EV##2, HV##2); EDGE1(EV##3, HV##3); \
} while (0)

#define FIN(ND) do { \
  const float inv_ = (ssum > 0.f) ? (1.0f / ssum) : 0.f; \
  float vx_ = fmaf(acc.x, inv_, bf2f(rv_cur.x)); \
  float vy_ = fmaf(acc.y, inv_, bf2f(rv_cur.y)); \
  float vz_ = fmaf(acc.z, inv_, bf2f(rv_cur.z)); \
  float vw_ = fmaf(acc.w, inv_, bf2f(rv_cur.w)); \
  vx_ = (vx_ > 0.f) ? vx_ : (__expf(vx_) - 1.f); \
  vy_ = (vy_ > 0.f) ? vy_ : (__expf(vy_) - 1.f); \
  vz_ = (vz_ > 0.f) ? vz_ : (__expf(vz_) - 1.f); \
  vw_ = (vw_ > 0.f) ? vw_ : (__expf(vw_) - 1.f); \
  vx_ += __shfl_xor(vx_, 16, 64); vx_ += __shfl_xor(vx_, 32, 64); \
  vy_ += __shfl_xor(vy_, 16, 64); vy_ += __shfl_xor(vy_, 32, 64); \
  vz_ += __shfl_xor(vz_, 16, 64); vz_ += __shfl_xor(vz_, 32, 64); \
  vw_ += __shfl_xor(vw_, 16, 64); vw_ += __shfl_xor(vw_, 32, 64); \
  if (lane < 16) { \
    float4 o_; \
    o_.x = vx_ * 0.25f; o_.y = vy_ * 0.25f; o_.z = vz_ * 0.25f; o_.w = vw_ * 0.25f; \
    *(float4*)(out + (size_t)(ND) * 64 + lane4) = o_; \
  } \
} while (0)

#define BOUNDARY() \
  while (p == nend) { \
    FIN(nu); \
    acc.x = 0.f; acc.y = 0.f; acc.z = 0.f; acc.w = 0.f; ssum = 0.f; \
    nu++; \
    nend = nendN; ern = ernN; rv_cur = rvN; \
    const int f1_ = (nu + 1 < N_NODES) ? (nu + 1) : (N_NODES - 1); \
    const int f2_ = (nu + 2 <= N_NODES) ? (nu + 2) : N_NODES; \
    nendN = RFL(rs[f2_]); \
    ernN = er[f1_ * 4 + head]; \
    rvN = *(const ushort4*)(resbuf + (size_t)f1_ * 256 + lane4); \
  }

__global__ __launch_bounds__(256, 4) void k_agg(
    const unsigned short* __restrict__ hbuf, const unsigned short* __restrict__ resbuf,
    const float* __restrict__ el, const float* __restrict__ er,
    const int* __restrict__ rs, const int* __restrict__ esrc,
    float* __restrict__ out)
{
  const int lane = threadIdx.x & 63;
  const int head = lane >> 4;
  const int lane4 = lane * 4;
  const int wid = blockIdx.x * 4 + (threadIdx.x >> 6);
  const int nW = gridDim.x * 4;

  const int n0 = (int)(((long long)wid * N_NODES) / nW);
  const int n1 = (int)(((long long)(wid + 1) * N_NODES) / nW);
  if (n0 >= n1) return;

  int nu = RFL(n0);
  const int p_end = RFL(rs[n1]);
  int nend = RFL(rs[nu + 1]);
  int f1 = (nu + 1 < N_NODES) ? (nu + 1) : (N_NODES - 1);
  int f2 = (nu + 2 <= N_NODES) ? (nu + 2) : N_NODES;
  int nendN = RFL(rs[f2]);
  float ern  = er[nu * 4 + head];
  float ernN = er[f1 * 4 + head];
  ushort4 rv_cur = *(const ushort4*)(resbuf + (size_t)nu * 256 + lane4);
  ushort4 rvN    = *(const ushort4*)(resbuf + (size_t)f1 * 256 + lane4);

  float4 acc = make_float4(0.f, 0.f, 0.f, 0.f);
  float ssum = 0.f;

  int4 snA, snB, snC, snD;
  float evA0, evA1, evA2, evA3, evB0, evB1, evB2, evB3;
  float evC0, evC1, evC2, evC3, evD0, evD1, evD2, evD3;
  ushort4 hvA0, hvA1, hvA2, hvA3, hvB0, hvB1, hvB2, hvB3;
  ushort4 hvC0, hvC1, hvC2, hvC3, hvD0, hvD1, hvD2, hvD3;

  int p = RFL(rs[nu]);
  if (p      < p_end) { LOADSN4(snA, p);      GATHER4(evA, hvA, snA); }
  if (p + 4  < p_end) { LOADSN4(snB, p + 4);  GATHER4(evB, hvB, snB); }
  if (p + 8  < p_end) { LOADSN4(snC, p + 8);  GATHER4(evC, hvC, snC); }
  if (p + 12 < p_end) { LOADSN4(snD, p + 12); }

  while (p < p_end) {
    // ---- step A (batch p)
    if (p + 12 < p_end) GATHER4(evD, hvD, snD);
    if (p + 16 < p_end) LOADSN4(snA, p + 16);
    BOUNDARY();
    COMPUTE4(evA, hvA);
    p += 4; if (p >= p_end) break;
    // ---- step B
    if (p + 12 < p_end) GATHER4(evA, hvA, snA);
    if (p + 16 < p_end) LOADSN4(snB, p + 16);
    BOUNDARY();
    COMPUTE4(evB, hvB);
    p += 4; if (p >= p_end) break;
    // ---- step C
    if (p + 12 < p_end) GATHER4(evB, hvB, snB);
    if (p + 16 < p_end) LOADSN4(snC, p + 16);
    BOUNDARY();
    COMPUTE4(evC, hvC);
    p += 4; if (p >= p_end) break;
    // ---- step D
    if (p + 12 < p_end) GATHER4(evC, hvC, snC);
    if (p + 16 < p_end) LOADSN4(snD, p + 16);
    BOUNDARY();
    COMPUTE4(evD, hvD);
    p += 4;
  }

  // drain: finalize last node + trailing zero-degree nodes
  while (nu < n1) {
    FIN(nu);
    acc.x = 0.f; acc.y = 0.f; acc.z = 0.f; acc.w = 0.f; ssum = 0.f;
    nu++;
    if (nu < n1) rv_cur = *(const ushort4*)(resbuf + (size_t)nu * 256 + lane4);
  }
}

// ---------------- BN stats over out (separate small pass) ----------------
__global__ __launch_bounds__(256) void k_bn_stats(const float* __restrict__ out,
                                                  float* __restrict__ bn)
{
  const int t = threadIdx.x;
  const int c4 = (t & 15) * 4;
  const int rg = t >> 4;
  float4 s = make_float4(0.f, 0.f, 0.f, 0.f);
  float4 q = make_float4(0.f, 0.f, 0.f, 0.f);
  for (int row = blockIdx.x * 16 + rg; row < N_NODES; row += gridDim.x * 16) {
    float4 v = *(const float4*)(out + (size_t)row * 64 + c4);
    s.x += v.x; s.y += v.y; s.z += v.z; s.w += v.w;
    q.x += v.x * v.x; q.y += v.y * v.y; q.z += v.z * v.z; q.w += v.w * v.w;
  }
  __shared__ float ls[64], lq[64];
  if (t < 64) { ls[t] = 0.f; lq[t] = 0.f; }
  __syncthreads();
  atomicAdd(&ls[c4 + 0], s.x); atomicAdd(&ls[c4 + 1], s.y);
  atomicAdd(&ls[c4 + 2], s.z); atomicAdd(&ls[c4 + 3], s.w);
  atomicAdd(&lq[c4 + 0], q.x); atomicAdd(&lq[c4 + 1], q.y);
  atomicAdd(&lq[c4 + 2], q.z); atomicAdd(&lq[c4 + 3], q.w);
  __syncthreads();
  if (t < 64) {
    atomicAdd(&bn[t], ls[t]);
    atomicAdd(&bn[64 + t], lq[t]);
  }
}

// ---------------- batchnorm apply ----------------
__global__ __launch_bounds__(256) void k_bn_apply(float* __restrict__ out,
                                                  const float* __restrict__ bn,
                                                  const float* __restrict__ gamma,
                                                  const float* __restrict__ beta)
{
  __shared__ float sc[64], sh[64];
  const int t = threadIdx.x;
  if (t < 64) {
    float mean = bn[t] * (1.0f / N_NODES);
    float var = bn[64 + t] * (1.0f / N_NODES) - mean * mean;
    float s = gamma[t] * rsqrtf(var + BN_EPS);
    sc[t] = s;
    sh[t] = beta[t] - mean * s;
  }
  __syncthreads();
  const int i = blockIdx.x * 256 + t;
  if (i >= N_NODES * 16) return;
  const int d0 = (i & 15) * 4;
  float4 v = *(float4*)(out + (size_t)i * 4);
  v.x = fmaf(v.x, sc[d0 + 0], sh[d0 + 0]);
  v.y = fmaf(v.y, sc[d0 + 1], sh[d0 + 1]);
  v.z = fmaf(v.z, sc[d0 + 2], sh[d0 + 2]);
  v.w = fmaf(v.w, sc[d0 + 3], sh[d0 + 3]);
  *(float4*)(out + (size_t)i * 4) = v;
}

extern "C" void kernel_launch(void* const* d_in, const int* in_sizes, int n_in,
                              void* d_out, int out_size, void* d_ws, size_t ws_size,
                              hipStream_t stream)
{
  const float* feats  = (const float*)d_in[0];
  const int*   src    = (const int*)d_in[1];
  const int*   dst    = (const int*)d_in[2];
  const float* fc_w   = (const float*)d_in[3];
  const float* attn_l = (const float*)d_in[4];
  const float* attn_r = (const float*)d_in[5];
  const float* res_w  = (const float*)d_in[6];
  const float* bias   = (const float*)d_in[7];
  const float* gamma  = (const float*)d_in[8];
  const float* beta   = (const float*)d_in[9];

  char* ws = (char*)d_ws;
  unsigned short* Ab     = (unsigned short*)(ws + OFF_AB);
  unsigned short* Bb     = (unsigned short*)(ws + OFF_BB);
  unsigned short* hbuf   = (unsigned short*)(ws + OFF_H);
  unsigned short* resbuf = (unsigned short*)(ws + OFF_RES);
  float* elb    = (float*)(ws + OFF_EL);
  float* erb    = (float*)(ws + OFF_ER);
  int*   deg    = (int*)(ws + OFF_DEG);
  int*   rsb    = (int*)(ws + OFF_RS);
  float* bnb    = (float*)(ws + OFF_BN);
  int*   esrc   = (int*)(ws + OFF_ESRC);
  int*   bsums  = (int*)(ws + OFF_BS);
  float* outp   = (float*)d_out;
  int*   rankp  = (int*)d_out;          // scratch: first 6.4 MB of out

  hipMemsetAsync(deg, 0, N_NODES * sizeof(int), stream);
  hipMemsetAsync(bnb, 0, 128 * sizeof(float), stream);

  k_pre<<<12539, 256, 0, stream>>>(feats, fc_w, res_w, dst, Ab, Bb, deg, hbuf, elb, rankp);
  k_scan1<<<98, 256, 0, stream>>>(deg, rsb, bsums);
  k_scan3<<<391, 256, 0, stream>>>(rsb, bsums, deg, esrc);
  k_place<<<6250, 256, 0, stream>>>(src, dst, rsb, rankp, esrc);
  k_mm<<<782, 256, 0, stream>>>(Ab, Bb, bias, attn_l, attn_r,
                                hbuf, resbuf, elb, erb);
  k_agg<<<4096, 256, 0, stream>>>(hbuf, resbuf, elb, erb, rsb, esrc, outp);
  k_bn_stats<<<256, 256, 0, stream>>>(outp, bnb);
  k_bn_apply<<<6250, 256, 0, stream>>>(outp, bnb, gamma, beta);
}